// Round 1
// 446.071 us; speedup vs baseline: 1.3838x; 1.3838x over previous
//
#include <hip/hip_runtime.h>

// Problem constants (B=64, C=D=64, H=W=64, K=1024)
#define K_CODES 1024
#define D_DIM   64
#define N_ROWS  262144      // B*H*W
#define HW      4096        // H*W
#define CHW     262144      // C*H*W
#define N_ELEM  16777216    // B*C*H*W
#define DECAY   0.99f
#define OMD     0.01f       // 1 - DECAY
#define EPS_F   1e-05f
#define MARGIN_BF 0.006f    // ~40 sigma of split-bf16 score noise (~1e-4)
#define FLAG_CAP 32768      // expected flags ~400 (0.15%)
#define SEG_CAP  2048       // per-code row cap (mean 256, Poisson max ~340)
#define NHB      64         // hist blocks (4096 rows each)

typedef __attribute__((ext_vector_type(8))) short bf16x8;  // 8 bf16 = 4 VGPRs
typedef __attribute__((ext_vector_type(4))) float f32x4;

// Workspace layout (bytes); [0,64) is the only zeroed region. All 16B-aligned.
// FLAGS and WFRAG temporally overlay SORT (dead before scatter writes it).
constexpr size_t OFF_LOSS    = 0;        // 1 double
constexpr size_t OFF_FLAGCNT = 8;        // 1 int
constexpr size_t ZERO_BYTES  = 64;
constexpr size_t OFF_W2F     = 64;       // 1024 f   -> 4160
constexpr size_t OFF_W2D     = 4160;     // 1024 d   -> 12352
constexpr size_t OFF_CS     = 12352;     // 1024 f   -> 16448
constexpr size_t OFF_GOFF    = 16448;    // 1025 i   -> 20608 (padded)
constexpr size_t OFF_DW      = 20608;    // 65536 f  -> 282752
constexpr size_t OFF_NEWW    = 282752;   // 65536 f  -> 544896
constexpr size_t OFF_IDX     = 544896;   // 262144 i -> 1593472
constexpr size_t OFF_HISTB   = 1593472;  // 64x1024 i -> 1855616
constexpr size_t OFF_SORT    = 1855616;  // 262144 i -> 2904192
constexpr size_t OFF_FLAGS   = 1855616;  // 32768 i (dead after refine)
constexpr size_t OFF_WFRAG   = 1986688;  // 131072 bf16 (dead after argmin) -> 2248832

__device__ __forceinline__ short f2bf(float f) {  // RNE float->bf16
    unsigned u = __float_as_uint(f);
    u += 0x7fffu + ((u >> 16) & 1u);
    return (short)(u >> 16);
}
__device__ __forceinline__ float bf2f(short h) {
    return __uint_as_float(((unsigned)(unsigned short)h) << 16);
}

// Async global->LDS, 16B per lane. LDS dest is wave-uniform base + lane*16
// (hardware semantics); our dest layout is linear in thread id so this holds.
__device__ __forceinline__ void gload_lds16(const float4* g, void* l) {
    __builtin_amdgcn_global_load_lds(
        (const __attribute__((address_space(1))) void*)g,
        (__attribute__((address_space(3))) void*)l, 16, 0, 0);
}

// One-time prep: W swizzled to bf16 hi/lo B-fragment pairs for 16x16x32 MFMA.
__global__ __launch_bounds__(256) void prep_kernel(
    const float* __restrict__ w, short* __restrict__ wfrag,
    float* __restrict__ w2f, double* __restrict__ w2d) {
    int t = threadIdx.x;
    if (blockIdx.x < 32) {
        int gid = blockIdx.x * 256 + t;  // (j<<7)|(h<<6)|L
        int j = gid >> 7, h = (gid >> 6) & 1, L = gid & 63;
        int code = j * 16 + (L & 15);
        int kb = h * 32 + ((L >> 4) << 3);
        const float* wp = w + code * D_DIM + kb;
        short hi[8], lo[8];
#pragma unroll
        for (int i = 0; i < 8; ++i) {
            float v = wp[i];
            short hb = f2bf(v);
            hi[i] = hb;
            lo[i] = f2bf(v - bf2f(hb));
        }
        short* dh = wfrag + (size_t)(((j * 2 + h) * 2 + 0) * 64 + L) * 8;
        short* dl = wfrag + (size_t)(((j * 2 + h) * 2 + 1) * 64 + L) * 8;
#pragma unroll
        for (int i = 0; i < 8; ++i) { dh[i] = hi[i]; dl[i] = lo[i]; }
    } else {
        int k = (blockIdx.x - 32) * 256 + t;
        const float* wk = w + k * D_DIM;
        float sf = 0.f; double sd = 0.0;
#pragma unroll
        for (int d = 0; d < D_DIM; ++d) {
            float wv = wk[d];
            sf = fmaf(wv, wv, sf);
            sd = fma((double)wv, (double)wv, sd);
        }
        w2f[k] = sf; w2d[k] = sd;
    }
}

// Split-bf16 MFMA argmin: block = 4 waves = 64 rows; near-ties flagged for
// fp64 refine. W fragments double-buffered through LDS via global_load_lds
// (buffer B unions with the dead-after-prologue xs staging array, so LDS
// stays 37888B -> 4 blocks/CU). Also emits xt = x row-major [row][64].
//
// SPILL FIX (R7): rocprof showed VGPR_Count=60 + WRITE_SIZE 374MB (~308MB
// scratch = 4096 blk x 256 thr x ~300B). __launch_bounds__(256,2) sets only
// the MIN waves/EU (VGPR cap) — the allocator still TARGETED 8 waves/EU and
// spilled to reach 60 VGPRs. amdgpu_waves_per_eu(2,4) caps the occupancy
// target at 4 waves/EU (<=128 VGPRs, spill-free); removing the barrier-
// crossing stg[4] prefetch (16 VGPRs) via global_load_lds cuts peak pressure.
__global__ __launch_bounds__(256) __attribute__((amdgpu_waves_per_eu(2, 4)))
void argmin_kernel(
    const float* __restrict__ inp, const short* __restrict__ wfrag,
    const float* __restrict__ w2f, int* __restrict__ idx_ws,
    float* __restrict__ out_idx_f, float* __restrict__ xt,
    int* __restrict__ flagcnt, int* __restrict__ flaglist) {
    __shared__ float w2s[K_CODES];
    __shared__ alignas(16) char smem_u[64 * 68 * 4];  // xs(17408B) / bufB(16KB) union
    __shared__ alignas(16) short bufA[8192];          // 16 KB
    float (*xs)[68] = (float (*)[68])smem_u;          // +4 pad per row
    short* bufB = (short*)smem_u;

    int t = threadIdx.x;
    ((float4*)w2s)[t] = ((const float4*)w2f)[t];

    int rowbase = blockIdx.x * 64;
    int b = rowbase >> 12, hwb = rowbase & (HW - 1);
    const float* xp = inp + (size_t)b * CHW + hwb;
    int lane = t & 63, wave = t >> 6;
#pragma unroll
    for (int it = 0; it < 16; ++it) {
        int d = wave * 16 + it;
        xs[lane][d] = xp[(size_t)d * HW + lane];  // coalesced 256B per d
    }
    __syncthreads();

    // xt side-product: coalesced row-major dump of this block's 64 rows
    float4* xt4 = (float4*)(xt + (size_t)rowbase * D_DIM);
#pragma unroll
    for (int i2 = 0; i2 < 4; ++i2) {
        int c2 = t + i2 * 256;
        xt4[c2] = ((const float4*)xs[c2 >> 4])[c2 & 15];
    }

    int q = lane >> 4, col = lane & 15;
    int rl = wave * 16 + col;  // A-fragment row m = lane&15
    bf16x8 ah0, ah1, al0, al1;
#pragma unroll
    for (int i = 0; i < 8; ++i) {
        float v0 = xs[rl][q * 8 + i];
        short h0 = f2bf(v0);
        ah0[i] = h0; al0[i] = f2bf(v0 - bf2f(h0));
        float v1 = xs[rl][q * 8 + 32 + i];
        short h1 = f2bf(v1);
        ah1[i] = h1; al1[i] = f2bf(v1 - bf2f(h1));
    }

    float best[4]  = {3.4e38f, 3.4e38f, 3.4e38f, 3.4e38f};
    float best2[4] = {3.4e38f, 3.4e38f, 3.4e38f, 3.4e38f};
    int   bk[4]    = {0, 0, 0, 0};
    const float4* wsrc = (const float4*)wfrag;

    // Prologue: issue supertile 0 into bufA. xs is still live here; bufB (its
    // alias) is first written at st=0 AFTER the loop-top barrier, by which
    // point all waves have finished the fragment build + xt dump above.
    {
        const float4* src = wsrc + t;
        char* nb = (char*)bufA + wave * 1024;
#pragma unroll
        for (int i2 = 0; i2 < 4; ++i2)
            gload_lds16(src + i2 * 256, nb + i2 * 4096);
    }

    for (int st = 0; st < 16; ++st) {
        // Single barrier per supertile: drains vmcnt(0) (buf[st&1] loads
        // landed) and orders last tile's reads before the next issue.
        asm volatile("s_waitcnt vmcnt(0)" ::: "memory");
        __syncthreads();
        if (st < 15) {
            const float4* src = wsrc + (size_t)(st + 1) * 1024 + t;
            char* nb = ((st & 1) ? (char*)bufA : (char*)bufB) + wave * 1024;
#pragma unroll
            for (int i2 = 0; i2 < 4; ++i2)
                gload_lds16(src + i2 * 256, nb + i2 * 4096);
        }
        const bf16x8* wt = (const bf16x8*)((st & 1) ? bufB : bufA);

#pragma unroll
        for (int jj = 0; jj < 4; ++jj) {
            int j = st * 4 + jj;
            bf16x8 bh0 = wt[(jj * 4 + 0) * 64 + lane];
            bf16x8 bl0 = wt[(jj * 4 + 1) * 64 + lane];
            bf16x8 bh1 = wt[(jj * 4 + 2) * 64 + lane];
            bf16x8 bl1 = wt[(jj * 4 + 3) * 64 + lane];
            f32x4 acc = {0.f, 0.f, 0.f, 0.f};
            acc = __builtin_amdgcn_mfma_f32_16x16x32_bf16(al0, bh0, acc, 0, 0, 0);
            acc = __builtin_amdgcn_mfma_f32_16x16x32_bf16(al1, bh1, acc, 0, 0, 0);
            acc = __builtin_amdgcn_mfma_f32_16x16x32_bf16(ah0, bl0, acc, 0, 0, 0);
            acc = __builtin_amdgcn_mfma_f32_16x16x32_bf16(ah1, bl1, acc, 0, 0, 0);
            acc = __builtin_amdgcn_mfma_f32_16x16x32_bf16(ah0, bh0, acc, 0, 0, 0);
            acc = __builtin_amdgcn_mfma_f32_16x16x32_bf16(ah1, bh1, acc, 0, 0, 0);
            float w2c = w2s[j * 16 + col];
            int c = j * 16 + col;
#pragma unroll
            for (int r = 0; r < 4; ++r) {
                float s = fmaf(-2.f, acc[r], w2c);
                bool lt = s < best[r];
                best2[r] = fminf(best2[r], fmaxf(s, best[r]));
                best[r]  = fminf(best[r], s);
                bk[r]    = lt ? c : bk[r];
            }
        }
    }

#pragma unroll
    for (int m = 1; m < 16; m <<= 1) {
#pragma unroll
        for (int r = 0; r < 4; ++r) {
            float ob  = __shfl_xor(best[r], m, 64);
            float ob2 = __shfl_xor(best2[r], m, 64);
            int   obk = __shfl_xor(bk[r], m, 64);
            float nb2 = fminf(fminf(best2[r], ob2), fmaxf(best[r], ob));
            int   nbk = ob < best[r] ? obk
                        : (best[r] < ob ? bk[r] : min(bk[r], obk));
            best[r]  = fminf(best[r], ob);
            best2[r] = nb2;
            bk[r]    = nbk;
        }
    }

    if (col == 0) {
#pragma unroll
        for (int r = 0; r < 4; ++r) {
            int row = rowbase + wave * 16 + q * 4 + r;  // C row = quad*4+reg
            idx_ws[row]    = bk[r];
            out_idx_f[row] = (float)bk[r];
            if (best2[r] - best[r] < MARGIN_BF) {
                int pos = atomicAdd(flagcnt, 1);
                if (pos < FLAG_CAP) flaglist[pos] = row;
            }
        }
    }
}

// fp64 rescan of flagged rows (exact); patches idx/out_idx_f before hist.
__global__ __launch_bounds__(256) void refine_kernel(
    const float* __restrict__ xt, const float* __restrict__ weight,
    const double* __restrict__ w2d, int* __restrict__ idx_ws,
    float* __restrict__ out_idx_f, const int* __restrict__ flagcnt,
    const int* __restrict__ flaglist) {
    int cnt = *flagcnt;
    if (cnt > FLAG_CAP) cnt = FLAG_CAP;

    __shared__ float  sx[D_DIM];
    __shared__ double sd[256];
    __shared__ int    si[256];
    int t = threadIdx.x;

    for (int r = blockIdx.x; r < cnt; r += gridDim.x) {
        int row = flaglist[r];
        if (t < D_DIM) sx[t] = xt[(size_t)row * D_DIM + t];
        __syncthreads();

        double x2 = 0.0;
#pragma unroll
        for (int d = 0; d < D_DIM; ++d) {
            double xv = (double)sx[d];
            x2 = fma(xv, xv, x2);
        }

        double bd = 1.0e300; int bi = 0;
#pragma unroll
        for (int jj = 0; jj < 4; ++jj) {
            int k = t + jj * 256;
            const float* wk = weight + k * D_DIM;
            double dot = 0.0;
#pragma unroll
            for (int d = 0; d < D_DIM; ++d)
                dot = fma((double)wk[d], (double)sx[d], dot);
            double dist = (x2 + w2d[k]) - 2.0 * dot;
            if (dist < bd) { bd = dist; bi = k; }
        }
        sd[t] = bd; si[t] = bi;
        __syncthreads();
        for (int s = 128; s > 0; s >>= 1) {
            if (t < s) {
                double od = sd[t + s]; int oi = si[t + s];
                if (od < sd[t] || (od == sd[t] && oi < si[t])) {
                    sd[t] = od; si[t] = oi;
                }
            }
            __syncthreads();
        }
        if (t == 0 && si[0] != idx_ws[row]) {
            idx_ws[row]    = si[0];
            out_idx_f[row] = (float)si[0];
        }
        __syncthreads();
    }
}

// Counting sort, pass 1: per-block LDS histogram of 4096 rows -> histb[b][k].
__global__ __launch_bounds__(256) void hist_kernel(
    const int* __restrict__ idx_ws, int* __restrict__ histb) {
    __shared__ int h[K_CODES];
    int t = threadIdx.x, b = blockIdx.x;
    for (int i = t; i < K_CODES; i += 256) h[i] = 0;
    __syncthreads();
    const int4* idx4 = (const int4*)idx_ws + b * 1024;
#pragma unroll
    for (int i = 0; i < 4; ++i) {
        int4 c = idx4[t + i * 256];
        atomicAdd(&h[c.x], 1); atomicAdd(&h[c.y], 1);
        atomicAdd(&h[c.z], 1); atomicAdd(&h[c.w], 1);
    }
    __syncthreads();
    for (int i = t; i < K_CODES; i += 256) histb[b * K_CODES + i] = h[i];
}

// Pass 2 (1 block, 1024 thr): column prefix over block histograms + global
// exclusive prefix -> cursors (in histb) + goff. Fused Laplace/csn.
__global__ __launch_bounds__(1024) void scan_kernel(
    int* __restrict__ histb, int* __restrict__ goff,
    const float* __restrict__ ema_cs, float* __restrict__ csbuf) {
    __shared__ int pre[K_CODES];
    __shared__ float red[K_CODES];
    int k = threadIdx.x;

    int s = 0;
    for (int b = 0; b < NHB; ++b) {
        int v = histb[b * K_CODES + k];
        histb[b * K_CODES + k] = s;  // local exclusive prefix
        s += v;
    }
    int cnt = s;

    pre[k] = cnt;
    __syncthreads();
    for (int d = 1; d < K_CODES; d <<= 1) {
        int v = (k >= d) ? pre[k - d] : 0;
        __syncthreads();
        if (k >= d) pre[k] += v;
        __syncthreads();
    }
    int base = pre[k] - cnt;
    goff[k] = base;
    if (k == K_CODES - 1) goff[K_CODES] = pre[k];

    for (int b = 0; b < NHB; ++b) histb[b * K_CODES + k] += base;

    float cs = ema_cs[k] * DECAY + OMD * (float)cnt;
    red[k] = cs;
    __syncthreads();
    for (int s2 = 512; s2 > 0; s2 >>= 1) {
        if (k < s2) red[k] += red[k + s2];
        __syncthreads();
    }
    float n = red[0];
    csbuf[k] = (cs + EPS_F) / (n + (float)K_CODES * EPS_F) * n;
}

// Pass 3: scatter row ids into code-sorted order via LDS cursors.
__global__ __launch_bounds__(256) void scatter_kernel(
    const int* __restrict__ idx_ws, const int* __restrict__ histb,
    int* __restrict__ sorted) {
    __shared__ int cur[K_CODES];
    int t = threadIdx.x, b = blockIdx.x;
    for (int i = t; i < K_CODES; i += 256) cur[i] = histb[b * K_CODES + i];
    __syncthreads();
    const int4* idx4 = (const int4*)idx_ws + b * 1024;
#pragma unroll
    for (int i = 0; i < 4; ++i) {
        int4 c = idx4[t + i * 256];
        int r0 = (b * 1024 + t + i * 256) * 4;
        sorted[atomicAdd(&cur[c.x], 1)] = r0 + 0;
        sorted[atomicAdd(&cur[c.y], 1)] = r0 + 1;
        sorted[atomicAdd(&cur[c.z], 1)] = r0 + 2;
        sorted[atomicAdd(&cur[c.w], 1)] = r0 + 3;
    }
}

// Pass 4: one block per code; gather xt rows (coalesced 256B), 2 chains for
// load ILP, LDS tree, direct dw store. Zero global atomics.
__global__ __launch_bounds__(256) void dwred_kernel(
    const float* __restrict__ xt, const int* __restrict__ sorted,
    const int* __restrict__ goff, float* __restrict__ dw) {
    __shared__ int   rows[SEG_CAP];
    __shared__ float red[256];
    int k = blockIdx.x, t = threadIdx.x;
    int base = goff[k];
    int cnt = goff[k + 1] - base;
    int cc = cnt > SEG_CAP ? SEG_CAP : cnt;

    for (int i = t; i < cc; i += 256) rows[i] = sorted[base + i];
    __syncthreads();

    int d = t & 63, sub = t >> 6;
    float a0 = 0.f, a1 = 0.f;
    int i = sub;
    for (; i + 4 < cc; i += 8) {
        a0 += xt[(size_t)rows[i] * D_DIM + d];
        a1 += xt[(size_t)rows[i + 4] * D_DIM + d];
    }
    for (; i < cc; i += 4) a0 += xt[(size_t)rows[i] * D_DIM + d];
    red[t] = a0 + a1;
    __syncthreads();
    if (t < 64) {
        dw[k * D_DIM + t] = red[t] + red[t + 64] + red[t + 128] + red[t + 192];
    }
}

// new_w = (ema_w*decay + (1-decay)*dw) / csbuf
__global__ __launch_bounds__(256) void emaw_kernel(
    const float* __restrict__ ema_w, const float* __restrict__ dw,
    const float* __restrict__ csbuf, float* __restrict__ new_w) {
    int i = blockIdx.x * 256 + threadIdx.x;
    new_w[i] = (ema_w[i] * DECAY + OMD * dw[i]) / csbuf[i >> 6];
}

// Gather updated codebook, straight-through output, commitment-loss partials.
__global__ __launch_bounds__(256) void out_kernel(
    const float* __restrict__ inp, const float* __restrict__ new_w,
    const int* __restrict__ idx_ws, float* __restrict__ out,
    double* __restrict__ loss_acc) {
    int row = blockIdx.x * 256 + threadIdx.x;
    int b  = row >> 12;
    int hw = row & (HW - 1);
    const float* xp = inp + (size_t)b * CHW + hw;
    float* op = out + 1 + (size_t)b * CHW + hw;  // out[0] is the loss scalar

    int k = idx_ws[row];
    const float* q = new_w + k * D_DIM;

    float lsum = 0.f;
#pragma unroll
    for (int d = 0; d < D_DIM; ++d) {
        float xv = xp[(size_t)d * HW];
        float qv = q[d];
        float diff = qv - xv;            // stop_gradient(quantized) - x
        lsum = fmaf(diff, diff, lsum);
        op[(size_t)d * HW] = xv + diff;  // x + (quantized - x)
    }

    __shared__ double lred[256];
    lred[threadIdx.x] = (double)lsum;
    __syncthreads();
    for (int s = 128; s > 0; s >>= 1) {
        if (threadIdx.x < s) lred[threadIdx.x] += lred[threadIdx.x + s];
        __syncthreads();
    }
    if (threadIdx.x == 0) atomicAdd(loss_acc, lred[0]);
}

__global__ void loss_final(const double* __restrict__ loss_acc,
                           float* __restrict__ out) {
    out[0] = (float)(0.25 * (*loss_acc / (double)N_ELEM));
}

extern "C" void kernel_launch(void* const* d_in, const int* in_sizes, int n_in,
                              void* d_out, int out_size, void* d_ws, size_t ws_size,
                              hipStream_t stream) {
    const float* inp    = (const float*)d_in[0];
    const float* weight = (const float*)d_in[1];
    const float* ema_cs = (const float*)d_in[2];
    const float* ema_w  = (const float*)d_in[3];
    float* out = (float*)d_out;

    char* ws = (char*)d_ws;
    double* loss_acc = (double*)(ws + OFF_LOSS);
    int*    flagcnt  = (int*)(ws + OFF_FLAGCNT);
    float*  w2f      = (float*)(ws + OFF_W2F);
    double* w2d      = (double*)(ws + OFF_W2D);
    float*  csbuf    = (float*)(ws + OFF_CS);
    int*    goff     = (int*)(ws + OFF_GOFF);
    float*  dw       = (float*)(ws + OFF_DW);
    float*  new_w    = (float*)(ws + OFF_NEWW);
    int*    idx_ws   = (int*)(ws + OFF_IDX);
    int*    histb    = (int*)(ws + OFF_HISTB);
    int*    sorted   = (int*)(ws + OFF_SORT);
    int*    flaglist = (int*)(ws + OFF_FLAGS);
    short*  wfrag    = (short*)(ws + OFF_WFRAG);

    float* xt        = out + 1;               // scratch: overwritten by out_kernel
    float* out_idx_f = out + 1 + (size_t)N_ELEM;

    hipMemsetAsync(ws, 0, ZERO_BYTES, stream);  // loss + flagcnt only

    prep_kernel<<<36, 256, 0, stream>>>(weight, wfrag, w2f, w2d);

    argmin_kernel<<<N_ROWS / 64, 256, 0, stream>>>(
        inp, wfrag, w2f, idx_ws, out_idx_f, xt, flagcnt, flaglist);

    refine_kernel<<<1024, 256, 0, stream>>>(
        xt, weight, w2d, idx_ws, out_idx_f, flagcnt, flaglist);

    hist_kernel<<<NHB, 256, 0, stream>>>(idx_ws, histb);

    scan_kernel<<<1, 1024, 0, stream>>>(histb, goff, ema_cs, csbuf);

    scatter_kernel<<<NHB, 256, 0, stream>>>(idx_ws, histb, sorted);

    dwred_kernel<<<K_CODES, 256, 0, stream>>>(xt, sorted, goff, dw);

    emaw_kernel<<<K_CODES * D_DIM / 256, 256, 0, stream>>>(ema_w, dw, csbuf, new_w);

    out_kernel<<<N_ROWS / 256, 256, 0, stream>>>(inp, new_w, idx_ws, out, loss_acc);

    loss_final<<<1, 1, 0, stream>>>(loss_acc, out);
}